// Round 8
// baseline (935.025 us; speedup 1.0000x reference)
//
#include <hip/hip_runtime.h>

// RecursiveEncoder on MI355X. B=16, H=256, S=16, C=5, L=6, N_LEAF=15625, N_INT=3906.
// R8: (1) dataflow reverted to R5 (bucket-gather A; R7 sequential-A regressed l5);
//     (2) levels 4..0 + head FUSED into one persistent kernel (grid=256, 1/CU
//         resident, device-scope spin barriers) — small levels were paying a full
//         latency-gated K-loop + launch gap each;
//     (3) prep+bucket merged (counters zeroed via hipMemsetAsync);
//     (4) leaf: 4 rows/wave ILP (R5: VALUBusy 54% at 2 rows).

#define B_ 16
#define H_ 256
#define NLEAF 15625
#define NINT 3906
#define GPERS 256

typedef __bf16 bf16_t;
typedef bf16_t bf16x8 __attribute__((ext_vector_type(8)));
typedef bf16_t bf16x4 __attribute__((ext_vector_type(4)));
typedef float f32x4 __attribute__((ext_vector_type(4)));

__device__ __forceinline__ void gl2lds16(const bf16_t* g, bf16_t* l) {
  __builtin_amdgcn_global_load_lds((const __attribute__((address_space(1))) void*)g,
                                   (__attribute__((address_space(3))) void*)l,
                                   16, 0, 0);
}

// ---------------- prep (240 blocks) + bucket (245 blocks) in one launch -------
__global__ __launch_bounds__(256) void prep_bucket_kernel(
    const float* __restrict__ W_node, bf16_t* __restrict__ Wt,
    const int* __restrict__ node_type, int* __restrict__ counters,
    int2* __restrict__ buckets) {
  const int tid = threadIdx.x;
  if (blockIdx.x < 240) {
    const int t = blockIdx.x / 80;
    const int kc = blockIdx.x % 80;
    const float* srcp = W_node + (size_t)t * 1280 * 256 + tid;
    bf16_t* dstp = Wt + ((size_t)(t * 256 + tid)) * 1280;
#pragma unroll
    for (int k0 = kc * 16; k0 < kc * 16 + 16; k0 += 8) {
      bf16x8 v;
#pragma unroll
      for (int j = 0; j < 8; ++j) v[j] = (bf16_t)srcp[(size_t)(k0 + j) * 256];
      *(bf16x8*)(dstp + k0) = v;
    }
    return;
  }
  // bucket part (counters pre-zeroed by hipMemsetAsync)
  __shared__ int lcnt[18];
  __shared__ int lbase[18];
  if (tid < 18) lcnt[tid] = 0;
  __syncthreads();
  int idx = (blockIdx.x - 240) * 256 + tid;
  bool active = idx < B_ * NINT;
  int t = 0, key = 0, mypos = 0;
  int2 e;
  int base = 0, nl_cap = 0;
  if (active) {
    int b = idx / NINT;
    int j = idx - b * NINT;
    int l, off;
    if (j >= 781)      { l = 5; off = 781; }
    else if (j >= 156) { l = 4; off = 156; }
    else if (j >= 31)  { l = 3; off = 31; }
    else if (j >= 6)   { l = 2; off = 6; }
    else if (j >= 1)   { l = 1; off = 1; }
    else               { l = 0; off = 0; }
    const int n_tab[6]    = {1, 5, 25, 125, 625, 3125};
    const int nn_tab[6]   = {5, 25, 125, 625, 3125, 15625};
    const int base_tab[6] = {0, 48, 288, 1488, 7488, 37488};
    int n_l = n_tab[l], nn = nn_tab[l];
    t = node_type[idx];
    int i = j - off;
    e.x = b * n_l + i;        // out row in f[l]
    e.y = b * nn + 5 * i;     // first child row in f[l+1]
    base = base_tab[l];
    nl_cap = B_ * n_l;
    key = l * 3 + t;
    mypos = atomicAdd(&lcnt[key], 1);
  }
  __syncthreads();
  if (tid < 18) {
    int c = lcnt[tid];
    lbase[tid] = c ? atomicAdd(&counters[tid], c) : 0;
  }
  __syncthreads();
  if (active) buckets[base + t * nl_cap + lbase[key] + mypos] = e;
}

// ---------------- leaf: 4 rows per wave iteration, bf16x4 stores --------------
__global__ __launch_bounds__(256) void leaf_kernel(
    const float* __restrict__ leaf_box, const float* __restrict__ leaf_sem,
    const float* __restrict__ W_box, const float* __restrict__ b_box,
    const float* __restrict__ W_sem, const float* __restrict__ b_sem,
    bf16_t* __restrict__ f6) {
  const int lane = threadIdx.x & 63;
  const int wave = threadIdx.x >> 6;
  const int h0 = lane * 4;
  float wb[4][4], ws[16][4], bb[4], bs[4];
#pragma unroll
  for (int j = 0; j < 4; ++j) {
    float4 v = *(const float4*)(W_box + j * H_ + h0);
    wb[j][0] = v.x; wb[j][1] = v.y; wb[j][2] = v.z; wb[j][3] = v.w;
  }
#pragma unroll
  for (int j = 0; j < 16; ++j) {
    float4 v = *(const float4*)(W_sem + j * H_ + h0);
    ws[j][0] = v.x; ws[j][1] = v.y; ws[j][2] = v.z; ws[j][3] = v.w;
  }
  {
    float4 v = *(const float4*)(b_box + h0);
    bb[0] = v.x; bb[1] = v.y; bb[2] = v.z; bb[3] = v.w;
    float4 u = *(const float4*)(b_sem + h0);
    bs[0] = u.x; bs[1] = u.y; bs[2] = u.z; bs[3] = u.w;
  }
  const int ROWS = B_ * NLEAF;  // 250000, %16 == 0
  const int stride = gridDim.x * 16;
  for (int row = blockIdx.x * 16 + wave * 4; row < ROWS; row += stride) {
    float4 bx[4]; float4 sv[4][4];
#pragma unroll
    for (int r = 0; r < 4; ++r) {
      bx[r] = *(const float4*)(leaf_box + (size_t)(row + r) * 4);
      const float4* sp = (const float4*)(leaf_sem + (size_t)(row + r) * 16);
      sv[r][0] = sp[0]; sv[r][1] = sp[1]; sv[r][2] = sp[2]; sv[r][3] = sp[3];
    }
#pragma unroll
    for (int r = 0; r < 4; ++r) {
      bf16x4 o;
#pragma unroll
      for (int c = 0; c < 4; ++c) {
        float s1 = fmaf(wb[0][c], bx[r].x, fmaf(wb[1][c], bx[r].y,
                   fmaf(wb[2][c], bx[r].z, fmaf(wb[3][c], bx[r].w, bb[c]))));
        float s2 = bs[c];
#pragma unroll
        for (int j = 0; j < 4; ++j) {
          s2 = fmaf(ws[4*j+0][c], sv[r][j].x, s2);
          s2 = fmaf(ws[4*j+1][c], sv[r][j].y, s2);
          s2 = fmaf(ws[4*j+2][c], sv[r][j].z, s2);
          s2 = fmaf(ws[4*j+3][c], sv[r][j].w, s2);
        }
        o[c] = (bf16_t)(fmaxf(s1, 0.f) + fmaxf(s2, 0.f));
      }
      *(bf16x4*)(f6 + (size_t)(row + r) * H_ + h0) = o;
    }
  }
}

// ---------------- shared level-tile body (R5 structure, proven best) ----------
__device__ __forceinline__ void level_tile(
    bf16_t* __restrict__ As, bf16_t* __restrict__ Bs,
    const bf16_t* __restrict__ src, bf16_t* __restrict__ dst,
    const int2* __restrict__ rd, int cnt,
    const bf16_t* __restrict__ wsrc, const float* __restrict__ b_node_t,
    const float* __restrict__ ibox, const float* __restrict__ W_box,
    const float* __restrict__ b_box, int n_l, int off_l, int tile0, int nblk) {
  const int tid = threadIdx.x;
  const int lane = tid & 63;
  const int wave = tid >> 6;
  const int wm = wave & 1, wn = wave >> 1;
  const int quad = lane >> 4;
  const int l15 = lane & 15;

  const int r8 = tid >> 3;
  const int sc = tid & 7;
  const bf16_t* aptr[4];
  const bf16_t* bptr[4];
#pragma unroll
  for (int i = 0; i < 4; ++i) {
    int r = i * 32 + r8;
    int gch = sc ^ ((r >> 1) & 7);
    int ai = tile0 + r;
    if (ai >= cnt) ai = cnt - 1;
    aptr[i] = src + (size_t)rd[ai].y * H_ + gch * 8;
    bptr[i] = wsrc + (size_t)r * 1280 + gch * 8;
  }

  f32x4 acc[4][4];
#pragma unroll
  for (int i = 0; i < 4; ++i)
#pragma unroll
    for (int j = 0; j < 4; ++j) acc[i][j] = (f32x4){0.f, 0.f, 0.f, 0.f};

  const int sw = (l15 >> 1) & 7;
  const int pc0 = (quad ^ sw) * 8;
  const int pc1 = ((4 + quad) ^ sw) * 8;

#define STAGE(buf, ks)                                            \
  {                                                               \
    const int ko = (ks) * 64;                                     \
    bf16_t* la = As + (buf) * 8192 + wave * 512;                  \
    bf16_t* lb = Bs + (buf) * 8192 + wave * 512;                  \
    _Pragma("unroll") for (int i = 0; i < 4; ++i)                 \
        gl2lds16(aptr[i] + ko, la + i * 2048);                    \
    _Pragma("unroll") for (int i = 0; i < 4; ++i)                 \
        gl2lds16(bptr[i] + ko, lb + i * 2048);                    \
  }

  STAGE(0, 0)
  for (int ks = 0; ks < 20; ++ks) {
    const int buf = ks & 1;
    __syncthreads();
    bf16x8 af0[4], af1[4], bf0[4], bf1[4];
#pragma unroll
    for (int am = 0; am < 4; ++am) {
      const bf16_t* rp = As + buf * 8192 + (wm * 64 + am * 16 + l15) * 64;
      af0[am] = *(const bf16x8*)(rp + pc0);
      af1[am] = *(const bf16x8*)(rp + pc1);
    }
#pragma unroll
    for (int bn = 0; bn < 4; ++bn) {
      const bf16_t* rp = Bs + buf * 8192 + (wn * 64 + bn * 16 + l15) * 64;
      bf0[bn] = *(const bf16x8*)(rp + pc0);
      bf1[bn] = *(const bf16x8*)(rp + pc1);
    }
    if (ks + 1 < 20) STAGE(buf ^ 1, ks + 1)
#pragma unroll
    for (int am = 0; am < 4; ++am)
#pragma unroll
      for (int bn = 0; bn < 4; ++bn)
        acc[am][bn] = __builtin_amdgcn_mfma_f32_16x16x32_bf16(af0[am], bf0[bn], acc[am][bn], 0, 0, 0);
#pragma unroll
    for (int am = 0; am < 4; ++am)
#pragma unroll
      for (int bn = 0; bn < 4; ++bn)
        acc[am][bn] = __builtin_amdgcn_mfma_f32_16x16x32_bf16(af1[am], bf1[bn], acc[am][bn], 0, 0, 0);
  }
#undef STAGE
  __syncthreads();  // drain last prefetch DMA + readers before LDS reuse

  float wbv[4][6];
#pragma unroll
  for (int bn = 0; bn < 4; ++bn) {
    int col = nblk * 128 + wn * 64 + bn * 16 + l15;
    wbv[bn][0] = W_box[col];
    wbv[bn][1] = W_box[H_ + col];
    wbv[bn][2] = W_box[2 * H_ + col];
    wbv[bn][3] = W_box[3 * H_ + col];
    wbv[bn][4] = b_box[col];
    wbv[bn][5] = b_node_t[col];
  }
#pragma unroll
  for (int am = 0; am < 4; ++am) {
    int orow[4]; float4 bxv[4]; bool valid[4];
#pragma unroll
    for (int r = 0; r < 4; ++r) {
      int gidx = tile0 + wm * 64 + am * 16 + quad * 4 + r;
      valid[r] = (gidx < cnt);
      int ic = valid[r] ? gidx : (cnt - 1);
      int orw = rd[ic].x;
      orow[r] = orw;
      int b = orw / n_l;
      int i = orw - b * n_l;
      bxv[r] = *(const float4*)(ibox + ((size_t)b * NINT + off_l + i) * 4);
    }
#pragma unroll
    for (int bn = 0; bn < 4; ++bn) {
      int col = nblk * 128 + wn * 64 + bn * 16 + l15;
#pragma unroll
      for (int r = 0; r < 4; ++r) {
        if (!valid[r]) continue;
        float y = fmaxf(acc[am][bn][r] + wbv[bn][5], 0.f);
        float be = fmaf(wbv[bn][0], bxv[r].x,
                   fmaf(wbv[bn][1], bxv[r].y,
                   fmaf(wbv[bn][2], bxv[r].z,
                   fmaf(wbv[bn][3], bxv[r].w, wbv[bn][4]))));
        be = fmaxf(be, 0.f);
        dst[(size_t)orow[r] * H_ + col] = (bf16_t)(y + be);
      }
    }
  }
}

// ---------------- level-5 (big) launch --------------------------------------
__global__ __launch_bounds__(256) void level5_kernel(
    const bf16_t* __restrict__ src, bf16_t* __restrict__ dst,
    const int2* __restrict__ bucket, const int* __restrict__ counters,
    const bf16_t* __restrict__ Wt, const float* __restrict__ b_node,
    const float* __restrict__ ibox, const float* __restrict__ W_box,
    const float* __restrict__ b_box) {
  __shared__ __align__(16) bf16_t As[2 * 128 * 64];
  __shared__ __align__(16) bf16_t Bs[2 * 128 * 64];
  const int t = blockIdx.y;
  const int cnt = counters[15 + t];
  const int tile0 = blockIdx.x * 128;
  if (tile0 >= cnt) return;
  const int nblk = blockIdx.z;
  level_tile(As, Bs, src, dst, bucket + 37488 + (size_t)t * (B_ * 3125), cnt,
             Wt + ((size_t)t * 256 + nblk * 128) * 1280, b_node + t * H_,
             ibox, W_box, b_box, 3125, 781, tile0, nblk);
}

// ---------------- persistent fused kernel: levels 4..0 + head -----------------
__device__ __forceinline__ void gbar(int* ctr) {
  __syncthreads();
  if (threadIdx.x == 0) {
    __threadfence();
    atomicAdd(ctr, 1);
    while (__hip_atomic_load(ctr, __ATOMIC_ACQUIRE, __HIP_MEMORY_SCOPE_AGENT) < GPERS)
      __builtin_amdgcn_s_sleep(1);
    __threadfence();
  }
  __syncthreads();
}

__global__ __launch_bounds__(256) void fused_kernel(
    const bf16_t* __restrict__ f5, bf16_t* __restrict__ f4,
    bf16_t* __restrict__ f3, bf16_t* __restrict__ f2,
    bf16_t* __restrict__ f1, bf16_t* __restrict__ f0,
    const int2* __restrict__ buckets, const int* __restrict__ counters,
    int* __restrict__ bars,
    const bf16_t* __restrict__ Wt, const float* __restrict__ b_node,
    const float* __restrict__ ibox, const float* __restrict__ W_box,
    const float* __restrict__ b_box,
    const float* __restrict__ eps, const float* __restrict__ W1,
    const float* __restrict__ b1, const float* __restrict__ Wmu,
    const float* __restrict__ bmu, const float* __restrict__ Wvar,
    const float* __restrict__ bvar, float* __restrict__ out) {
  __shared__ __align__(16) bf16_t As[2 * 128 * 64];
  __shared__ __align__(16) bf16_t Bs[2 * 128 * 64];

  const bf16_t* fin[5]  = {f5, f4, f3, f2, f1};
  bf16_t* fout[5]       = {f4, f3, f2, f1, f0};
  const int nl_tab[5]   = {625, 125, 25, 5, 1};
  const int off_tab[5]  = {156, 31, 6, 1, 0};
  const int base_tab[5] = {7488, 1488, 288, 48, 0};

#pragma unroll 1
  for (int li = 0; li < 5; ++li) {
    const int l = 4 - li;
    const int c0 = counters[l * 3 + 0];
    const int c1 = counters[l * 3 + 1];
    const int c2 = counters[l * 3 + 2];
    const int T0 = (c0 + 127) >> 7, T1 = (c1 + 127) >> 7, T2 = (c2 + 127) >> 7;
    const int W = 2 * (T0 + T1 + T2);
    const int cap = B_ * nl_tab[li];
#pragma unroll 1
    for (int w = blockIdx.x; w < W; w += GPERS) {
      int nblk = w & 1, q = w >> 1;
      int t, tile, cnt;
      if (q < T0)           { t = 0; tile = q;           cnt = c0; }
      else if (q < T0 + T1) { t = 1; tile = q - T0;      cnt = c1; }
      else                  { t = 2; tile = q - T0 - T1; cnt = c2; }
      level_tile(As, Bs, fin[li], fout[li],
                 buckets + base_tab[li] + (size_t)t * cap, cnt,
                 Wt + ((size_t)t * 256 + nblk * 128) * 1280, b_node + t * H_,
                 ibox, W_box, b_box, nl_tab[li], off_tab[li], tile * 128, nblk);
    }
    gbar(bars + li);
  }

  if (blockIdx.x >= B_) return;
  __shared__ float root[256];
  __shared__ float enc[256];
  int b = blockIdx.x, h = threadIdx.x;
  root[h] = (float)f0[b * H_ + h];
  __syncthreads();
  float a = b1[h];
#pragma unroll 8
  for (int k = 0; k < 256; ++k) a = fmaf(root[k], W1[k * H_ + h], a);
  enc[h] = fmaxf(a, 0.f);
  __syncthreads();
  float m = bmu[h], lv = bvar[h];
#pragma unroll 8
  for (int k = 0; k < 256; ++k) {
    float e = enc[k];
    m = fmaf(e, Wmu[k * H_ + h], m);
    lv = fmaf(e, Wvar[k * H_ + h], lv);
  }
  float stdv = expf(0.5f * lv);
  float kld = 1.f + lv - m * m - expf(lv);
  out[b * 512 + h] = eps[b * H_ + h] * stdv + m;
  out[b * 512 + 256 + h] = kld;
}

extern "C" void kernel_launch(void* const* d_in, const int* in_sizes, int n_in,
                              void* d_out, int out_size, void* d_ws, size_t ws_size,
                              hipStream_t stream) {
  const float* leaf_box     = (const float*)d_in[0];
  const float* leaf_sem     = (const float*)d_in[1];
  const float* internal_box = (const float*)d_in[2];
  const int*   node_type    = (const int*)d_in[3];
  const float* eps          = (const float*)d_in[4];
  const float* W_box        = (const float*)d_in[5];
  const float* b_box        = (const float*)d_in[6];
  const float* W_sem        = (const float*)d_in[7];
  const float* b_sem        = (const float*)d_in[8];
  const float* W_node       = (const float*)d_in[9];
  const float* b_node       = (const float*)d_in[10];
  const float* W1           = (const float*)d_in[11];
  const float* b1           = (const float*)d_in[12];
  const float* Wmu          = (const float*)d_in[13];
  const float* bmu          = (const float*)d_in[14];
  const float* Wvar         = (const float*)d_in[15];
  const float* bvar         = (const float*)d_in[16];
  float* out = (float*)d_out;

  char* p = (char*)d_ws;
  auto alloc = [&](size_t bytes) {
    char* r = p;
    p += (bytes + 255) & ~(size_t)255;
    return r;
  };
  bf16_t* Wt = (bf16_t*)alloc((size_t)3 * 256 * 1280 * 2);
  const int n_tab[7] = {1, 5, 25, 125, 625, 3125, 15625};
  bf16_t* f[7];
  for (int l = 0; l <= 6; ++l) f[l] = (bf16_t*)alloc((size_t)B_ * n_tab[l] * H_ * 2);
  int* counters = (int*)alloc(24 * 4);  // 18 bucket counters + 5 barrier slots
  int* bars = counters + 18;
  int2* buckets = (int2*)alloc((size_t)187488 * 8);

  hipMemsetAsync(counters, 0, 24 * 4, stream);
  hipLaunchKernelGGL(prep_bucket_kernel, dim3(485), dim3(256), 0, stream,
                     W_node, Wt, node_type, counters, buckets);
  hipLaunchKernelGGL(leaf_kernel, dim3(2048), dim3(256), 0, stream,
                     leaf_box, leaf_sem, W_box, b_box, W_sem, b_sem, f[6]);
  hipLaunchKernelGGL(level5_kernel, dim3(391, 3, 2), dim3(256), 0, stream,
                     f[6], f[5], buckets, counters, Wt, b_node,
                     internal_box, W_box, b_box);
  hipLaunchKernelGGL(fused_kernel, dim3(GPERS), dim3(256), 0, stream,
                     f[5], f[4], f[3], f[2], f[1], f[0],
                     buckets, counters, bars, Wt, b_node,
                     internal_box, W_box, b_box,
                     eps, W1, b1, Wmu, bmu, Wvar, bvar, out);
}

// Round 9
// 420.052 us; speedup vs baseline: 2.2260x; 2.2260x over previous
//
#include <hip/hip_runtime.h>

// RecursiveEncoder on MI355X. B=16, H=256, S=16, C=5, L=6, N_LEAF=15625, N_INT=3906.
// R9: 4 launches. (1) prep+bucket+leaf merged (leaf independent of prep/bucket);
//     (2) level5 (proven R5 tile); (3) level4; (4) tail = l3+l2+l1+l0+head fused
//     across 48 persistent blocks with RMW-poll barriers (R8's 256-spinner
//     s_sleep(1) load-flood starved the memory system -> 728us; 48 pollers at
//     s_sleep(32) is ~37 polls/us, negligible).

#define B_ 16
#define H_ 256
#define NLEAF 15625
#define NINT 3906
#define TAILB 48

typedef __bf16 bf16_t;
typedef bf16_t bf16x8 __attribute__((ext_vector_type(8)));
typedef bf16_t bf16x4 __attribute__((ext_vector_type(4)));
typedef float f32x4 __attribute__((ext_vector_type(4)));

__device__ __forceinline__ void gl2lds16(const bf16_t* g, bf16_t* l) {
  __builtin_amdgcn_global_load_lds((const __attribute__((address_space(1))) void*)g,
                                   (__attribute__((address_space(3))) void*)l,
                                   16, 0, 0);
}

// ---------------- launch 1: prep (240) + bucket (245) + leaf (2048) ----------
__global__ __launch_bounds__(256) void front_kernel(
    const float* __restrict__ W_node, bf16_t* __restrict__ Wt,
    const int* __restrict__ node_type, int* __restrict__ counters,
    int2* __restrict__ buckets,
    const float* __restrict__ leaf_box, const float* __restrict__ leaf_sem,
    const float* __restrict__ W_box, const float* __restrict__ b_box,
    const float* __restrict__ W_sem, const float* __restrict__ b_sem,
    bf16_t* __restrict__ f6) {
  const int tid = threadIdx.x;
  const int bx = blockIdx.x;
  if (bx < 240) {  // ---- prep: W_node fp32 -> Wt bf16 [t][h][k]
    const int t = bx / 80;
    const int kc = bx % 80;
    const float* srcp = W_node + (size_t)t * 1280 * 256 + tid;
    bf16_t* dstp = Wt + ((size_t)(t * 256 + tid)) * 1280;
#pragma unroll
    for (int k0 = kc * 16; k0 < kc * 16 + 16; k0 += 8) {
      bf16x8 v;
#pragma unroll
      for (int j = 0; j < 8; ++j) v[j] = (bf16_t)srcp[(size_t)(k0 + j) * 256];
      *(bf16x8*)(dstp + k0) = v;
    }
    return;
  }
  if (bx < 485) {  // ---- bucket (counters pre-zeroed by hipMemsetAsync)
    __shared__ int lcnt[18];
    __shared__ int lbase[18];
    if (tid < 18) lcnt[tid] = 0;
    __syncthreads();
    int idx = (bx - 240) * 256 + tid;
    bool active = idx < B_ * NINT;
    int t = 0, key = 0, mypos = 0;
    int2 e;
    int base = 0, nl_cap = 0;
    if (active) {
      int b = idx / NINT;
      int j = idx - b * NINT;
      int l, off;
      if (j >= 781)      { l = 5; off = 781; }
      else if (j >= 156) { l = 4; off = 156; }
      else if (j >= 31)  { l = 3; off = 31; }
      else if (j >= 6)   { l = 2; off = 6; }
      else if (j >= 1)   { l = 1; off = 1; }
      else               { l = 0; off = 0; }
      const int n_tab[6]    = {1, 5, 25, 125, 625, 3125};
      const int nn_tab[6]   = {5, 25, 125, 625, 3125, 15625};
      const int base_tab[6] = {0, 48, 288, 1488, 7488, 37488};
      int n_l = n_tab[l], nn = nn_tab[l];
      t = node_type[idx];
      int i = j - off;
      e.x = b * n_l + i;
      e.y = b * nn + 5 * i;
      base = base_tab[l];
      nl_cap = B_ * n_l;
      key = l * 3 + t;
      mypos = atomicAdd(&lcnt[key], 1);
    }
    __syncthreads();
    if (tid < 18) {
      int c = lcnt[tid];
      lbase[tid] = c ? atomicAdd(&counters[tid], c) : 0;
    }
    __syncthreads();
    if (active) buckets[base + t * nl_cap + lbase[key] + mypos] = e;
    return;
  }
  // ---- leaf: 4 rows per wave iteration
  const int lane = tid & 63;
  const int wave = tid >> 6;
  const int h0 = lane * 4;
  float wb[4][4], ws[16][4], bb[4], bs[4];
#pragma unroll
  for (int j = 0; j < 4; ++j) {
    float4 v = *(const float4*)(W_box + j * H_ + h0);
    wb[j][0] = v.x; wb[j][1] = v.y; wb[j][2] = v.z; wb[j][3] = v.w;
  }
#pragma unroll
  for (int j = 0; j < 16; ++j) {
    float4 v = *(const float4*)(W_sem + j * H_ + h0);
    ws[j][0] = v.x; ws[j][1] = v.y; ws[j][2] = v.z; ws[j][3] = v.w;
  }
  {
    float4 v = *(const float4*)(b_box + h0);
    bb[0] = v.x; bb[1] = v.y; bb[2] = v.z; bb[3] = v.w;
    float4 u = *(const float4*)(b_sem + h0);
    bs[0] = u.x; bs[1] = u.y; bs[2] = u.z; bs[3] = u.w;
  }
  const int ROWS = B_ * NLEAF;  // 250000, %16 == 0
  const int NB = 2048;
  const int stride = NB * 16;
  for (int row = (bx - 485) * 16 + wave * 4; row < ROWS; row += stride) {
    float4 bx4[4]; float4 sv[4][4];
#pragma unroll
    for (int r = 0; r < 4; ++r) {
      bx4[r] = *(const float4*)(leaf_box + (size_t)(row + r) * 4);
      const float4* sp = (const float4*)(leaf_sem + (size_t)(row + r) * 16);
      sv[r][0] = sp[0]; sv[r][1] = sp[1]; sv[r][2] = sp[2]; sv[r][3] = sp[3];
    }
#pragma unroll
    for (int r = 0; r < 4; ++r) {
      bf16x4 o;
#pragma unroll
      for (int c = 0; c < 4; ++c) {
        float s1 = fmaf(wb[0][c], bx4[r].x, fmaf(wb[1][c], bx4[r].y,
                   fmaf(wb[2][c], bx4[r].z, fmaf(wb[3][c], bx4[r].w, bb[c]))));
        float s2 = bs[c];
#pragma unroll
        for (int j = 0; j < 4; ++j) {
          s2 = fmaf(ws[4*j+0][c], sv[r][j].x, s2);
          s2 = fmaf(ws[4*j+1][c], sv[r][j].y, s2);
          s2 = fmaf(ws[4*j+2][c], sv[r][j].z, s2);
          s2 = fmaf(ws[4*j+3][c], sv[r][j].w, s2);
        }
        o[c] = (bf16_t)(fmaxf(s1, 0.f) + fmaxf(s2, 0.f));
      }
      *(bf16x4*)(f6 + (size_t)(row + r) * H_ + h0) = o;
    }
  }
}

// ---------------- shared level-tile body (R5 structure, proven best) ----------
__device__ __forceinline__ void level_tile(
    bf16_t* __restrict__ As, bf16_t* __restrict__ Bs,
    const bf16_t* __restrict__ src, bf16_t* __restrict__ dst,
    const int2* __restrict__ rd, int cnt,
    const bf16_t* __restrict__ wsrc, const float* __restrict__ b_node_t,
    const float* __restrict__ ibox, const float* __restrict__ W_box,
    const float* __restrict__ b_box, int n_l, int off_l, int tile0, int nblk) {
  const int tid = threadIdx.x;
  const int lane = tid & 63;
  const int wave = tid >> 6;
  const int wm = wave & 1, wn = wave >> 1;
  const int quad = lane >> 4;
  const int l15 = lane & 15;

  const int r8 = tid >> 3;
  const int sc = tid & 7;
  const bf16_t* aptr[4];
  const bf16_t* bptr[4];
#pragma unroll
  for (int i = 0; i < 4; ++i) {
    int r = i * 32 + r8;
    int gch = sc ^ ((r >> 1) & 7);
    int ai = tile0 + r;
    if (ai >= cnt) ai = cnt - 1;
    aptr[i] = src + (size_t)rd[ai].y * H_ + gch * 8;
    bptr[i] = wsrc + (size_t)r * 1280 + gch * 8;
  }

  f32x4 acc[4][4];
#pragma unroll
  for (int i = 0; i < 4; ++i)
#pragma unroll
    for (int j = 0; j < 4; ++j) acc[i][j] = (f32x4){0.f, 0.f, 0.f, 0.f};

  const int sw = (l15 >> 1) & 7;
  const int pc0 = (quad ^ sw) * 8;
  const int pc1 = ((4 + quad) ^ sw) * 8;

#define STAGE(buf, ks)                                            \
  {                                                               \
    const int ko = (ks) * 64;                                     \
    bf16_t* la = As + (buf) * 8192 + wave * 512;                  \
    bf16_t* lb = Bs + (buf) * 8192 + wave * 512;                  \
    _Pragma("unroll") for (int i = 0; i < 4; ++i)                 \
        gl2lds16(aptr[i] + ko, la + i * 2048);                    \
    _Pragma("unroll") for (int i = 0; i < 4; ++i)                 \
        gl2lds16(bptr[i] + ko, lb + i * 2048);                    \
  }

  STAGE(0, 0)
  for (int ks = 0; ks < 20; ++ks) {
    const int buf = ks & 1;
    __syncthreads();
    bf16x8 af0[4], af1[4], bf0[4], bf1[4];
#pragma unroll
    for (int am = 0; am < 4; ++am) {
      const bf16_t* rp = As + buf * 8192 + (wm * 64 + am * 16 + l15) * 64;
      af0[am] = *(const bf16x8*)(rp + pc0);
      af1[am] = *(const bf16x8*)(rp + pc1);
    }
#pragma unroll
    for (int bn = 0; bn < 4; ++bn) {
      const bf16_t* rp = Bs + buf * 8192 + (wn * 64 + bn * 16 + l15) * 64;
      bf0[bn] = *(const bf16x8*)(rp + pc0);
      bf1[bn] = *(const bf16x8*)(rp + pc1);
    }
    if (ks + 1 < 20) STAGE(buf ^ 1, ks + 1)
#pragma unroll
    for (int am = 0; am < 4; ++am)
#pragma unroll
      for (int bn = 0; bn < 4; ++bn)
        acc[am][bn] = __builtin_amdgcn_mfma_f32_16x16x32_bf16(af0[am], bf0[bn], acc[am][bn], 0, 0, 0);
#pragma unroll
    for (int am = 0; am < 4; ++am)
#pragma unroll
      for (int bn = 0; bn < 4; ++bn)
        acc[am][bn] = __builtin_amdgcn_mfma_f32_16x16x32_bf16(af1[am], bf1[bn], acc[am][bn], 0, 0, 0);
  }
#undef STAGE
  __syncthreads();  // drain before LDS reuse by caller

  float wbv[4][6];
#pragma unroll
  for (int bn = 0; bn < 4; ++bn) {
    int col = nblk * 128 + wn * 64 + bn * 16 + l15;
    wbv[bn][0] = W_box[col];
    wbv[bn][1] = W_box[H_ + col];
    wbv[bn][2] = W_box[2 * H_ + col];
    wbv[bn][3] = W_box[3 * H_ + col];
    wbv[bn][4] = b_box[col];
    wbv[bn][5] = b_node_t[col];
  }
#pragma unroll
  for (int am = 0; am < 4; ++am) {
    int orow[4]; float4 bxv[4]; bool valid[4];
#pragma unroll
    for (int r = 0; r < 4; ++r) {
      int gidx = tile0 + wm * 64 + am * 16 + quad * 4 + r;
      valid[r] = (gidx < cnt);
      int ic = valid[r] ? gidx : (cnt - 1);
      int orw = rd[ic].x;
      orow[r] = orw;
      int b = orw / n_l;
      int i = orw - b * n_l;
      bxv[r] = *(const float4*)(ibox + ((size_t)b * NINT + off_l + i) * 4);
    }
#pragma unroll
    for (int bn = 0; bn < 4; ++bn) {
      int col = nblk * 128 + wn * 64 + bn * 16 + l15;
#pragma unroll
      for (int r = 0; r < 4; ++r) {
        if (!valid[r]) continue;
        float y = fmaxf(acc[am][bn][r] + wbv[bn][5], 0.f);
        float be = fmaf(wbv[bn][0], bxv[r].x,
                   fmaf(wbv[bn][1], bxv[r].y,
                   fmaf(wbv[bn][2], bxv[r].z,
                   fmaf(wbv[bn][3], bxv[r].w, wbv[bn][4]))));
        be = fmaxf(be, 0.f);
        dst[(size_t)orow[r] * H_ + col] = (bf16_t)(y + be);
      }
    }
  }
}

// ---------------- launch 2/3: level 5 and level 4 ----------------------------
__global__ __launch_bounds__(256) void level_kernel(
    const bf16_t* __restrict__ src, bf16_t* __restrict__ dst,
    const int2* __restrict__ bucket, const int* __restrict__ counters,
    const bf16_t* __restrict__ Wt, const float* __restrict__ b_node,
    const float* __restrict__ ibox, const float* __restrict__ W_box,
    const float* __restrict__ b_box, int n_l, int off_l) {
  __shared__ __align__(16) bf16_t As[2 * 128 * 64];
  __shared__ __align__(16) bf16_t Bs[2 * 128 * 64];
  const int t = blockIdx.y;
  const int cnt = counters[t];
  const int tile0 = blockIdx.x * 128;
  if (tile0 >= cnt) return;
  const int nblk = blockIdx.z;
  level_tile(As, Bs, src, dst, bucket + (size_t)t * (B_ * n_l), cnt,
             Wt + ((size_t)t * 256 + nblk * 128) * 1280, b_node + t * H_,
             ibox, W_box, b_box, n_l, off_l, tile0, nblk);
}

// ---------------- launch 4: tail = l3+l2+l1+l0+head, 48 blocks ----------------
__device__ __forceinline__ void gbar(int* ctr) {
  __syncthreads();
  if (threadIdx.x == 0) {
    __threadfence();
    atomicAdd(ctr, 1);
    while (atomicOr(ctr, 0) < TAILB) __builtin_amdgcn_s_sleep(32);
    __threadfence();
  }
  __syncthreads();
}

__global__ __launch_bounds__(256) void tail_kernel(
    const bf16_t* __restrict__ f4, bf16_t* __restrict__ f3,
    bf16_t* __restrict__ f2, bf16_t* __restrict__ f1, bf16_t* __restrict__ f0,
    const int2* __restrict__ buckets, const int* __restrict__ counters,
    int* __restrict__ bars,
    const bf16_t* __restrict__ Wt, const float* __restrict__ b_node,
    const float* __restrict__ ibox, const float* __restrict__ W_box,
    const float* __restrict__ b_box,
    const float* __restrict__ eps, const float* __restrict__ W1,
    const float* __restrict__ b1, const float* __restrict__ Wmu,
    const float* __restrict__ bmu, const float* __restrict__ Wvar,
    const float* __restrict__ bvar, float* __restrict__ out) {
  __shared__ __align__(16) bf16_t As[2 * 128 * 64];
  __shared__ __align__(16) bf16_t Bs[2 * 128 * 64];

  const bf16_t* fin[4]  = {f4, f3, f2, f1};
  bf16_t* fout[4]       = {f3, f2, f1, f0};
  const int nl_tab[4]   = {125, 25, 5, 1};
  const int off_tab[4]  = {31, 6, 1, 0};
  const int base_tab[4] = {1488, 288, 48, 0};

#pragma unroll 1
  for (int li = 0; li < 4; ++li) {
    const int l = 3 - li;
    const int c0 = counters[l * 3 + 0];
    const int c1 = counters[l * 3 + 1];
    const int c2 = counters[l * 3 + 2];
    const int T0 = (c0 + 127) >> 7, T1 = (c1 + 127) >> 7, T2 = (c2 + 127) >> 7;
    const int W = 2 * (T0 + T1 + T2);
    const int cap = B_ * nl_tab[li];
#pragma unroll 1
    for (int w = blockIdx.x; w < W; w += TAILB) {
      int nblk = w & 1, q = w >> 1;
      int t, tile, cnt;
      if (q < T0)           { t = 0; tile = q;           cnt = c0; }
      else if (q < T0 + T1) { t = 1; tile = q - T0;      cnt = c1; }
      else                  { t = 2; tile = q - T0 - T1; cnt = c2; }
      level_tile(As, Bs, fin[li], fout[li],
                 buckets + base_tab[li] + (size_t)t * cap, cnt,
                 Wt + ((size_t)t * 256 + nblk * 128) * 1280, b_node + t * H_,
                 ibox, W_box, b_box, nl_tab[li], off_tab[li], tile * 128, nblk);
    }
    gbar(bars + li);
  }

  if (blockIdx.x >= B_) return;
  float* root = (float*)As;        // reuse tile LDS
  float* enc = root + 256;
  int b = blockIdx.x, h = threadIdx.x;
  root[h] = (float)f0[b * H_ + h];
  __syncthreads();
  float a = b1[h];
#pragma unroll 8
  for (int k = 0; k < 256; ++k) a = fmaf(root[k], W1[k * H_ + h], a);
  enc[h] = fmaxf(a, 0.f);
  __syncthreads();
  float m = bmu[h], lv = bvar[h];
#pragma unroll 8
  for (int k = 0; k < 256; ++k) {
    float e = enc[k];
    m = fmaf(e, Wmu[k * H_ + h], m);
    lv = fmaf(e, Wvar[k * H_ + h], lv);
  }
  float stdv = expf(0.5f * lv);
  float kld = 1.f + lv - m * m - expf(lv);
  out[b * 512 + h] = eps[b * H_ + h] * stdv + m;
  out[b * 512 + 256 + h] = kld;
}

extern "C" void kernel_launch(void* const* d_in, const int* in_sizes, int n_in,
                              void* d_out, int out_size, void* d_ws, size_t ws_size,
                              hipStream_t stream) {
  const float* leaf_box     = (const float*)d_in[0];
  const float* leaf_sem     = (const float*)d_in[1];
  const float* internal_box = (const float*)d_in[2];
  const int*   node_type    = (const int*)d_in[3];
  const float* eps          = (const float*)d_in[4];
  const float* W_box        = (const float*)d_in[5];
  const float* b_box        = (const float*)d_in[6];
  const float* W_sem        = (const float*)d_in[7];
  const float* b_sem        = (const float*)d_in[8];
  const float* W_node       = (const float*)d_in[9];
  const float* b_node       = (const float*)d_in[10];
  const float* W1           = (const float*)d_in[11];
  const float* b1           = (const float*)d_in[12];
  const float* Wmu          = (const float*)d_in[13];
  const float* bmu          = (const float*)d_in[14];
  const float* Wvar         = (const float*)d_in[15];
  const float* bvar         = (const float*)d_in[16];
  float* out = (float*)d_out;

  char* p = (char*)d_ws;
  auto alloc = [&](size_t bytes) {
    char* r = p;
    p += (bytes + 255) & ~(size_t)255;
    return r;
  };
  bf16_t* Wt = (bf16_t*)alloc((size_t)3 * 256 * 1280 * 2);
  const int n_tab[7] = {1, 5, 25, 125, 625, 3125, 15625};
  bf16_t* f[7];
  for (int l = 0; l <= 6; ++l) f[l] = (bf16_t*)alloc((size_t)B_ * n_tab[l] * H_ * 2);
  int* counters = (int*)alloc(24 * 4);  // 18 bucket counters + 4 barrier slots
  int* bars = counters + 18;
  int2* buckets = (int2*)alloc((size_t)187488 * 8);

  hipMemsetAsync(counters, 0, 24 * 4, stream);
  hipLaunchKernelGGL(front_kernel, dim3(2533), dim3(256), 0, stream,
                     W_node, Wt, node_type, counters, buckets,
                     leaf_box, leaf_sem, W_box, b_box, W_sem, b_sem, f[6]);
  hipLaunchKernelGGL(level_kernel, dim3(391, 3, 2), dim3(256), 0, stream,
                     f[6], f[5], buckets + 37488, counters + 15, Wt, b_node,
                     internal_box, W_box, b_box, 3125, 781);
  hipLaunchKernelGGL(level_kernel, dim3(79, 3, 2), dim3(256), 0, stream,
                     f[5], f[4], buckets + 7488, counters + 12, Wt, b_node,
                     internal_box, W_box, b_box, 625, 156);
  hipLaunchKernelGGL(tail_kernel, dim3(TAILB), dim3(256), 0, stream,
                     f[4], f[3], f[2], f[1], f[0],
                     buckets, counters, bars, Wt, b_node,
                     internal_box, W_box, b_box,
                     eps, W1, b1, Wmu, bmu, Wvar, bvar, out);
}